// Round 8
// baseline (434.243 us; speedup 1.0000x reference)
//
#include <hip/hip_runtime.h>
#include <math.h>

// Mesh encoder: 4x (spiral conv + ELU + sparse pool) + final GEMM.
// VERTS = [65536, 16384, 4096, 1024, 256], SEQ=9, CH=[3,32,64,128,256], B=16.
//
// R7: edge-m-rows MFMA conv, batch->XCD pinning (bid%8==b%8), 3-MFMA hi/lo
// error split, atomic pool-scatter [b][r][co].
// R8: VMEM-instruction diet — xp4 float4 table for L0 gathers, eidx[e][16]
// precomputed spiral-vertex tables (kills col->idx chain; int2/int4 loads),
// L0 ES=4, vectorized row/val epilogue loads.

#define SEQL 9

typedef __attribute__((ext_vector_type(8))) short bf16x8;
typedef __attribute__((ext_vector_type(4))) float f32x4;

__device__ __forceinline__ unsigned short f2bf_rne(float f) {
    unsigned u = __builtin_bit_cast(unsigned, f);
    u = (u + 0x7FFFu + ((u >> 16) & 1u)) >> 16;
    return (unsigned short)u;
}
__device__ __forceinline__ float bf2f(unsigned short h) {
    unsigned u = ((unsigned)h) << 16;
    return __builtin_bit_cast(float, u);
}

// split 8 fp32 -> bf16 hi (trunc) + bf16 lo (trunc of exact residual)
__device__ __forceinline__ void cvt8(const float* xf, bf16x8& ah, bf16x8& al) {
    unsigned hu[4], lu[4];
#pragma unroll
    for (int p = 0; p < 4; ++p) {
        const unsigned u0 = __builtin_bit_cast(unsigned, xf[2 * p]);
        const unsigned u1 = __builtin_bit_cast(unsigned, xf[2 * p + 1]);
        const float h0 = __builtin_bit_cast(float, u0 & 0xFFFF0000u);
        const float h1 = __builtin_bit_cast(float, u1 & 0xFFFF0000u);
        const float l0 = xf[2 * p] - h0;
        const float l1 = xf[2 * p + 1] - h1;
        hu[p] = __builtin_amdgcn_perm(u1, u0, 0x07060302u);
        lu[p] = __builtin_amdgcn_perm(__builtin_bit_cast(unsigned, l1),
                                      __builtin_bit_cast(unsigned, l0),
                                      0x07060302u);
    }
    struct U4 { unsigned a, b, c, d; };
    ah = __builtin_bit_cast(bf16x8, U4{hu[0], hu[1], hu[2], hu[3]});
    al = __builtin_bit_cast(bf16x8, U4{lu[0], lu[1], lu[2], lu[3]});
}

// W [9*CIN][COUT] fp32 -> WTh/WTl [COUT][K] bf16; k -> (s=k/CINP, c=k%CINP),
// zero-padded where s>=9 or c>=CIN.
template<int CIN, int CINP, int COUT, int K>
__global__ __launch_bounds__(256)
void wt_prep(const float* __restrict__ W, unsigned short* __restrict__ WTh,
             unsigned short* __restrict__ WTl)
{
    const int t = blockIdx.x * 256 + threadIdx.x;
    if (t >= COUT * K) return;
    const int co = t / K, k = t % K;
    const int s = k / CINP, c = k % CINP;
    float w = (s < 9 && c < CIN) ? W[(size_t)(s * CIN + c) * COUT + co] : 0.0f;
    unsigned short h = f2bf_rne(w);
    WTh[t] = h;
    WTl[t] = f2bf_rne(w - bf2f(h));
}

// xp4[b][v] = (x[b][v][0], x[b][v][1], x[b][v][2], 0)
__global__ __launch_bounds__(256)
void build_xp4(const float* __restrict__ x, float* __restrict__ xp4)
{
    const int t = blockIdx.x * 256 + threadIdx.x;   // 16*65536
    const float* p = x + (size_t)t * 3;
    *(float4*)(xp4 + (size_t)t * 4) = make_float4(p[0], p[1], p[2], 0.0f);
}

// eidx[e][slot] = idx[col[e]][slot] for slot<9 else 0, per level, concatenated.
__global__ __launch_bounds__(256)
void build_eidx(const int* __restrict__ c0, const int* __restrict__ i0,
                const int* __restrict__ c1, const int* __restrict__ i1,
                const int* __restrict__ c2, const int* __restrict__ i2,
                const int* __restrict__ c3, const int* __restrict__ i3,
                int* __restrict__ E)   // [65280][16]
{
    const int t = blockIdx.x * 256 + threadIdx.x;   // 65280*16
    if (t >= 65280 * 16) return;
    const int e = t >> 4, slot = t & 15;
    int v = 0;
    const int* col; const int* idx; int el;
    if (e < 49152)      { col = c0; idx = i0; el = e; }
    else if (e < 61440) { col = c1; idx = i1; el = e - 49152; }
    else if (e < 64512) { col = c2; idx = i2; el = e - 61440; }
    else                { col = c3; idx = i3; el = e - 64512; }
    if (slot < 9) v = idx[col[el] * SEQL + slot];
    E[t] = v;
}

// Wave = ES groups of 16 edges x 1 batch x CS-slice of couts.
// A rows = 16 edges (lane&15); k-slot j of lane group g covers k=g*8+j within
// each 32-k step. eidx gives spiral verts directly (no col/idx chain).
template<int CIN, int CINP, int COUT, int K, int ES, int CS, int BPB>
__global__ __launch_bounds__(256)
void conv_pool_mfma(const float* __restrict__ xin,   // [16][NV][CINP] (xp4 for L0)
                    const int* __restrict__ eidx,    // [nnz][16]
                    const int* __restrict__ row, const float* __restrict__ val,
                    const unsigned short* __restrict__ WTh,
                    const unsigned short* __restrict__ WTl,
                    const float* __restrict__ bias,
                    float* __restrict__ xout,        // [16][NVOUT][COUT], zeroed
                    int NV, int NVOUT)
{
    constexpr int NT  = COUT / 16 / CS;
    constexpr int EGB = BPB / CS;

    const int tid  = threadIdx.x;
    const int lane = tid & 63, wid = tid >> 6;
    const int b16  = lane & 15, g = lane >> 4;

    const int bid  = blockIdx.x;
    const int q    = bid & 7, rr = bid >> 3;
    const int pass = rr / BPB, j = rr % BPB;
    const int b    = q + 8 * pass;                  // batch (XCD-pinned)
    const int cs   = j / EGB, egb = j % EGB;
    const int co0  = cs * (NT * 16);
    const int wg   = egb * 4 + wid;
    const int e_base = wg * (ES * 16);

    f32x4 acc[ES][NT];
#pragma unroll
    for (int es = 0; es < ES; ++es)
#pragma unroll
        for (int nt = 0; nt < NT; ++nt) {
            const float bv = bias[co0 + nt * 16 + b16];
            acc[es][nt] = (f32x4){bv, bv, bv, bv};
        }

    if constexpr (CINP == 4) {
        // L0: K=64, 2 k-steps; lane j: s = ks*8 + g*2 + j/4, c = j%4.
        // eidx slots >=9 are 0 and W rows s>=9 are 0 -> no guards needed.
#pragma unroll
        for (int ks = 0; ks < 2; ++ks) {
            bf16x8 wh[NT], wl[NT];
#pragma unroll
            for (int nt = 0; nt < NT; ++nt) {
                const size_t wo = (size_t)(co0 + nt * 16 + b16) * K + ks * 32 + g * 8;
                wh[nt] = *(const bf16x8*)(WTh + wo);
                wl[nt] = *(const bf16x8*)(WTl + wo);
            }
            const int s0 = ks * 8 + g * 2;
#pragma unroll
            for (int es = 0; es < ES; ++es) {
                const int e = e_base + es * 16 + b16;
                const int2 ev = *(const int2*)(eidx + e * 16 + s0);
                float xf[8];
                *(float4*)&xf[0] = *(const float4*)(xin + ((size_t)b * NV + ev.x) * 4);
                *(float4*)&xf[4] = *(const float4*)(xin + ((size_t)b * NV + ev.y) * 4);
                bf16x8 ah, al; cvt8(xf, ah, al);
#pragma unroll
                for (int nt = 0; nt < NT; ++nt) {
                    acc[es][nt] = __builtin_amdgcn_mfma_f32_16x16x32_bf16(ah, wh[nt], acc[es][nt], 0, 0, 0);
                    acc[es][nt] = __builtin_amdgcn_mfma_f32_16x16x32_bf16(al, wh[nt], acc[es][nt], 0, 0, 0);
                    acc[es][nt] = __builtin_amdgcn_mfma_f32_16x16x32_bf16(ah, wl[nt], acc[es][nt], 0, 0, 0);
                }
            }
        }
    } else {
        constexpr int KPS = CIN / 32;
        // s blocked in groups of 4 so eidx loads are one int4 per group.
#pragma unroll 1
        for (int sq = 0; sq < 3; ++sq) {
            int4 v4[ES];
#pragma unroll
            for (int es = 0; es < ES; ++es) {
                const int e = e_base + es * 16 + b16;
                v4[es] = *(const int4*)(eidx + e * 16 + sq * 4);
            }
            constexpr int SS_MAX = 4;   // sq=2 uses only ss=0 (s=8)
#pragma unroll
            for (int ss = 0; ss < SS_MAX; ++ss) {
                const int s = sq * 4 + ss;
                if (s >= SEQL) break;
#pragma unroll
                for (int kk = 0; kk < KPS; ++kk) {
                    const int ksl = s * KPS + kk;
                    bf16x8 wh[NT], wl[NT];
#pragma unroll
                    for (int nt = 0; nt < NT; ++nt) {
                        const size_t wo = (size_t)(co0 + nt * 16 + b16) * K + ksl * 32 + g * 8;
                        wh[nt] = *(const bf16x8*)(WTh + wo);
                        wl[nt] = *(const bf16x8*)(WTl + wo);
                    }
#pragma unroll
                    for (int es = 0; es < ES; ++es) {
                        const int vi = (ss == 0) ? v4[es].x : (ss == 1) ? v4[es].y
                                     : (ss == 2) ? v4[es].z : v4[es].w;
                        const float* xp = xin + ((size_t)b * NV + vi) * CIN + kk * 32 + g * 8;
                        float xf[8];
                        *(float4*)&xf[0] = *(const float4*)xp;
                        *(float4*)&xf[4] = *(const float4*)(xp + 4);
                        bf16x8 ah, al; cvt8(xf, ah, al);
#pragma unroll
                        for (int nt = 0; nt < NT; ++nt) {
                            acc[es][nt] = __builtin_amdgcn_mfma_f32_16x16x32_bf16(ah, wh[nt], acc[es][nt], 0, 0, 0);
                            acc[es][nt] = __builtin_amdgcn_mfma_f32_16x16x32_bf16(al, wh[nt], acc[es][nt], 0, 0, 0);
                            acc[es][nt] = __builtin_amdgcn_mfma_f32_16x16x32_bf16(ah, wl[nt], acc[es][nt], 0, 0, 0);
                        }
                    }
                }
            }
        }
    }

    // D: col=lane&15 (co_local), row=(lane>>4)*4+reg (edge m-row) [m89]
#pragma unroll
    for (int es = 0; es < ES; ++es) {
        const int eq = e_base + es * 16 + g * 4;
        const int4   r4 = *(const int4*)(row + eq);
        const float4 v4 = *(const float4*)(val + eq);
        const int   ra[4] = {r4.x, r4.y, r4.z, r4.w};
        const float va[4] = {v4.x, v4.y, v4.z, v4.w};
#pragma unroll
        for (int qq = 0; qq < 4; ++qq) {
#pragma unroll
            for (int nt = 0; nt < NT; ++nt) {
                float y = acc[es][nt][qq];
                y = (y > 0.0f) ? y : __expf(y) - 1.0f;
                atomicAdd(xout + ((size_t)b * NVOUT + ra[qq]) * COUT + co0 + nt * 16 + b16,
                          va[qq] * y);
            }
        }
    }
}

// Final GEMM partials: part[jblk][b][l] = sum_{j in blk} x4[b][j]*Wf[j][l]
__global__ __launch_bounds__(256)
void final_gemm_partial(const float* __restrict__ x4,   // [16][65536]
                        const float* __restrict__ Wf,   // [65536][256]
                        float* __restrict__ part)       // [256][16][256]
{
    __shared__ float xs[256 * 20];
    const int j0 = blockIdx.x * 256;
    const int t  = threadIdx.x;

#pragma unroll
    for (int it = 0; it < 16; ++it)
        xs[t * 20 + it] = x4[(size_t)it * 65536 + j0 + t];
    __syncthreads();

    float acc[16];
#pragma unroll
    for (int b = 0; b < 16; ++b) acc[b] = 0.0f;

#pragma unroll 4
    for (int jj = 0; jj < 256; ++jj) {
        const float w = Wf[(size_t)(j0 + jj) * 256 + t];
#pragma unroll
        for (int b4 = 0; b4 < 4; ++b4) {
            const float4 xv = *(const float4*)(xs + jj * 20 + b4 * 4);
            acc[b4 * 4 + 0] = fmaf(xv.x, w, acc[b4 * 4 + 0]);
            acc[b4 * 4 + 1] = fmaf(xv.y, w, acc[b4 * 4 + 1]);
            acc[b4 * 4 + 2] = fmaf(xv.z, w, acc[b4 * 4 + 2]);
            acc[b4 * 4 + 3] = fmaf(xv.w, w, acc[b4 * 4 + 3]);
        }
    }
#pragma unroll
    for (int b = 0; b < 16; ++b)
        part[(size_t)blockIdx.x * 4096 + b * 256 + t] = acc[b];
}

__global__ __launch_bounds__(256)
void final_reduce(const float* __restrict__ part, const float* __restrict__ bf,
                  float* __restrict__ out)
{
    const int b = blockIdx.x, l = threadIdx.x;   // 16 x 256
    float s = 0.0f;
    for (int jb = 0; jb < 256; ++jb) s += part[(size_t)jb * 4096 + b * 256 + l];
    out[b * 256 + l] = s + bf[l];
}

extern "C" void kernel_launch(void* const* d_in, const int* in_sizes, int n_in,
                              void* d_out, int out_size, void* d_ws, size_t ws_size,
                              hipStream_t stream)
{
    const float* x    = (const float*)d_in[0];
    const int*   idx0 = (const int*)d_in[1];
    const int*   row0 = (const int*)d_in[2];
    const int*   col0 = (const int*)d_in[3];
    const float* val0 = (const float*)d_in[4];
    const float* W0   = (const float*)d_in[5];
    const float* b0   = (const float*)d_in[6];
    const int*   idx1 = (const int*)d_in[7];
    const int*   row1 = (const int*)d_in[8];
    const int*   col1 = (const int*)d_in[9];
    const float* val1 = (const float*)d_in[10];
    const float* W1   = (const float*)d_in[11];
    const float* b1   = (const float*)d_in[12];
    const int*   idx2 = (const int*)d_in[13];
    const int*   row2 = (const int*)d_in[14];
    const int*   col2 = (const int*)d_in[15];
    const float* val2 = (const float*)d_in[16];
    const float* W2   = (const float*)d_in[17];
    const float* b2   = (const float*)d_in[18];
    const int*   idx3 = (const int*)d_in[19];
    const int*   row3 = (const int*)d_in[20];
    const int*   col3 = (const int*)d_in[21];
    const float* val3 = (const float*)d_in[22];
    const float* W3   = (const float*)d_in[23];
    const float* b3   = (const float*)d_in[24];
    const float* Wf   = (const float*)d_in[25];
    const float* bf   = (const float*)d_in[26];
    float* out = (float*)d_out;

    float* ws = (float*)d_ws;
    // Aliased timeline (float offsets):
    float* x1   = ws + 0;         // [16][16384][32]  live L0->L1
    float* xp4  = ws + 8388608;   // [16][65536][4]   live prep->L0 (= x2 region)
    float* x2   = ws + 8388608;   // [16][4096][64]   live L1->L2 (zeroed post-L0)
    float* x3   = ws + 0;         // [16][1024][128]  live L2->L3 (x1 dead)
    float* x4   = ws + 2097152;   // [16][256][256]   live L3->final
    float* part = ws + 3145728;   // [256][16][256]   final phase
    unsigned short* wt = (unsigned short*)(ws + 12582912);
    unsigned short *WTh0 = wt,          *WTl0 = wt + 2048;
    unsigned short *WTh1 = wt + 4096,   *WTl1 = wt + 22528;
    unsigned short *WTh2 = wt + 40960,  *WTl2 = wt + 114688;
    unsigned short *WTh3 = wt + 188416, *WTl3 = wt + 483328;  // end 778240 u16
    int* EIDX = (int*)(ws + 12972032);  // [65280][16] ints -> end ~14.02M floats (56.1 MB)
    int* E0 = EIDX;
    int* E1 = EIDX + 49152 * 16;
    int* E2 = EIDX + 61440 * 16;
    int* E3 = EIDX + 64512 * 16;

    // prep (tiny)
    wt_prep<3,   4,  32,   64><<<   8, 256, 0, stream>>>(W0, WTh0, WTl0);
    wt_prep<32,  32, 64,  288><<<  72, 256, 0, stream>>>(W1, WTh1, WTl1);
    wt_prep<64,  64, 128, 576><<< 288, 256, 0, stream>>>(W2, WTh2, WTl2);
    wt_prep<128, 128, 256, 1152><<<1152, 256, 0, stream>>>(W3, WTh3, WTl3);
    build_eidx<<<4080, 256, 0, stream>>>(col0, idx0, col1, idx1, col2, idx2,
                                         col3, idx3, EIDX);
    build_xp4<<<4096, 256, 0, stream>>>(x, xp4);

    // L0: xp4 -> x1; nnz=49152, ES=4, CS=1, BPB=192
    hipMemsetAsync(x1, 0, (size_t)8388608 * 4, stream);
    conv_pool_mfma<3, 4, 32, 64, 4, 1, 192><<<3072, 256, 0, stream>>>(
        xp4, E0, row0, val0, WTh0, WTl0, b0, x1, 65536, 16384);

    // L1: x1 -> x2; nnz=12288, ES=4, CS=1, BPB=48  (xp4 dead -> x2 reuse)
    hipMemsetAsync(x2, 0, (size_t)4194304 * 4, stream);
    conv_pool_mfma<32, 32, 64, 288, 4, 1, 48><<<768, 256, 0, stream>>>(
        x1, E1, row1, val1, WTh1, WTl1, b1, x2, 16384, 4096);

    // L2 + L3 (x1 dead -> zero x3|x4 region in one memset)
    hipMemsetAsync(x3, 0, (size_t)3145728 * 4, stream);
    // L2: nnz=3072, ES=4, CS=2, BPB=24
    conv_pool_mfma<64, 64, 128, 576, 4, 2, 24><<<384, 256, 0, stream>>>(
        x2, E2, row2, val2, WTh2, WTl2, b2, x3, 4096, 1024);
    // L3: nnz=768, ES=4, CS=4, BPB=12
    conv_pool_mfma<128, 128, 256, 1152, 4, 4, 12><<<192, 256, 0, stream>>>(
        x3, E3, row3, val3, WTh3, WTl3, b3, x4, 1024, 256);

    // final GEMM: out[16,256] = bf + x4_flat[16,65536] @ Wf[65536,256]
    final_gemm_partial<<<256, 256, 0, stream>>>(x4, Wf, part);
    final_reduce<<<16, 256, 0, stream>>>(part, bf, out);
}